// Round 1
// baseline (521.082 us; speedup 1.0000x reference)
//
#include <hip/hip_runtime.h>

// CrossSymmetricModal: two cross-attention branches, all heavy math as bf16 MFMA NT-GEMM.
// B=16, C=256, L=1024.  Output [16][512][1024] fp32.

typedef short bf16x8 __attribute__((ext_vector_type(8)));   // 8 bf16 in 4 VGPRs (guide-verified typedef)
typedef float f32x4 __attribute__((ext_vector_type(4)));

__device__ __forceinline__ unsigned short f2bf(float f) {
    union { float f; unsigned u; } v; v.f = f;
    unsigned r = v.u + 0x7fffu + ((v.u >> 16) & 1u);   // RNE
    return (unsigned short)(r >> 16);
}
__device__ __forceinline__ float bf2f(unsigned short h) {
    union { unsigned u; float f; } v; v.u = ((unsigned)h) << 16;
    return v.f;
}
__device__ __forceinline__ float ldval(const float* p) { return *p; }
__device__ __forceinline__ float ldval(const unsigned short* p) { return bf2f(*p); }

// ---------------------------------------------------------------------------
// NT GEMM: C[i,j] = alpha * sum_k A[i*lda+k]*B[j*ldb+k] + bias_row[i] + bias_col[j]
// A: M x K row-major (bf16), B: N x K row-major (bf16). M,N mult of 128, K mult of 32.
// 128x128 tile, BK=32, 4 waves in 2x2, each wave 4x4 of 16x16x32 MFMA.
// LDS rows padded 32->40 elems (80B) => <=2-way bank conflicts on ds_read_b128 (free).
// ---------------------------------------------------------------------------
#define TM 128
#define TN 128
#define BK 32
#define LSTR 40

template<bool OUT_BF16>
__global__ __launch_bounds__(256)
void gemm_nt(const unsigned short* __restrict__ A, const unsigned short* __restrict__ B,
             void* __restrict__ C,
             int K, int lda, int ldb, int ldc,
             long sA, long sB, long sC,
             float alpha, const float* __restrict__ bias_row, const float* __restrict__ bias_col)
{
    __shared__ unsigned short lA[TM * LSTR];
    __shared__ unsigned short lB[TN * LSTR];
    const int bz = blockIdx.z;
    const unsigned short* Ab = A + sA * bz;
    const unsigned short* Bb = B + sB * bz;
    const int i0 = blockIdx.y * TM;
    const int j0 = blockIdx.x * TN;
    const int t = threadIdx.x;
    const int lane = t & 63;
    const int wave = t >> 6;
    const int wm = wave & 1, wn = wave >> 1;
    const int srow = t >> 2, sq = t & 3;           // staging: 4 lanes x 16B per row

    const unsigned short* Ap = Ab + (long)(i0 + srow) * lda + sq * 8;
    const unsigned short* Bp = Bb + (long)(j0 + srow) * ldb + sq * 8;
    const long a64 = (long)64 * lda, b64 = (long)64 * ldb;

    f32x4 acc[4][4];
#pragma unroll
    for (int a_ = 0; a_ < 4; ++a_)
#pragma unroll
        for (int b_ = 0; b_ < 4; ++b_)
            acc[a_][b_] = (f32x4){0.f, 0.f, 0.f, 0.f};

    uint4 pa0 = *(const uint4*)(Ap);
    uint4 pa1 = *(const uint4*)(Ap + a64);
    uint4 pb0 = *(const uint4*)(Bp);
    uint4 pb1 = *(const uint4*)(Bp + b64);

    const int frow = lane & 15;
    const int fk = (lane >> 4) * 8;

    int k0 = 0;
    while (true) {
        __syncthreads();
        *(uint4*)(&lA[srow * LSTR + sq * 8]) = pa0;
        *(uint4*)(&lA[(srow + 64) * LSTR + sq * 8]) = pa1;
        *(uint4*)(&lB[srow * LSTR + sq * 8]) = pb0;
        *(uint4*)(&lB[(srow + 64) * LSTR + sq * 8]) = pb1;
        __syncthreads();
        const bool more = (k0 + BK < K);
        if (more) {
            pa0 = *(const uint4*)(Ap + k0 + BK);
            pa1 = *(const uint4*)(Ap + a64 + k0 + BK);
            pb0 = *(const uint4*)(Bp + k0 + BK);
            pb1 = *(const uint4*)(Bp + b64 + k0 + BK);
        }
        bf16x8 af[4], bfr[4];
#pragma unroll
        for (int mt = 0; mt < 4; ++mt)
            af[mt] = *(const bf16x8*)(&lA[(wm * 64 + mt * 16 + frow) * LSTR + fk]);
#pragma unroll
        for (int nt = 0; nt < 4; ++nt)
            bfr[nt] = *(const bf16x8*)(&lB[(wn * 64 + nt * 16 + frow) * LSTR + fk]);
#pragma unroll
        for (int mt = 0; mt < 4; ++mt)
#pragma unroll
            for (int nt = 0; nt < 4; ++nt)
                acc[mt][nt] = __builtin_amdgcn_mfma_f32_16x16x32_bf16(af[mt], bfr[nt], acc[mt][nt], 0, 0, 0);
        if (!more) break;
        k0 += BK;
    }

    const int lr = (lane >> 4) * 4;   // C/D: row=(lane>>4)*4+reg, col=lane&15 (m89/m91 verified)
    const int lc = lane & 15;
#pragma unroll
    for (int mt = 0; mt < 4; ++mt) {
#pragma unroll
        for (int nt = 0; nt < 4; ++nt) {
            const int col = j0 + wn * 64 + nt * 16 + lc;
            const float bc = bias_col ? bias_col[col] : 0.f;
#pragma unroll
            for (int r = 0; r < 4; ++r) {
                const int row = i0 + wm * 64 + mt * 16 + lr + r;
                const float br = bias_row ? bias_row[row] : 0.f;
                const float val = acc[mt][nt][r] * alpha + br + bc;
                const long off = sC * bz + (long)row * ldc + col;
                if (OUT_BF16) ((unsigned short*)C)[off] = f2bf(val);
                else          ((float*)C)[off] = val;
            }
        }
    }
}

// ---------------------------------------------------------------------------
// im2col (K=3, pad=1):  x [B][256][1024] -> xt [B][1024][768] bf16,
// xt[b][l][ci*3+j] = x[b][ci][l+j-1]
// ---------------------------------------------------------------------------
template<typename T>
__global__ __launch_bounds__(256)
void im2col3(const T* __restrict__ x, unsigned short* __restrict__ xt)
{
    const int bz = blockIdx.z;
    const int l0 = blockIdx.x * 64;
    __shared__ unsigned short tile[256 * 66];   // [ci][ll], ll = l-l0+1
    const T* xb = x + (long)bz * 256 * 1024;
    for (int idx = threadIdx.x; idx < 256 * 66; idx += 256) {
        const int ci = idx / 66, ll = idx - ci * 66;
        const int l = l0 + ll - 1;
        const float v = (l >= 0 && l < 1024) ? ldval(xb + (long)ci * 1024 + l) : 0.f;
        tile[ci * 66 + ll] = f2bf(v);
    }
    __syncthreads();
    unsigned short* xtb = xt + ((long)bz * 1024 + l0) * 768;
    for (int i = threadIdx.x; i < 64 * 96; i += 256) {
        const int r = i / 96, cq = i - r * 96;
        const int kbase = cq * 8;
        union { uint4 u; unsigned short s[8]; } o;
#pragma unroll
        for (int e = 0; e < 8; ++e) {
            const int k = kbase + e;
            const int ci = k / 3, j = k - ci * 3;
            o.s[e] = tile[ci * 66 + r + j];
        }
        *(uint4*)(xtb + (long)r * 768 + kbase) = o.u;
    }
}

// ---------------------------------------------------------------------------
// Cin=1 convs from clinical: kTa [B][L][C], qTb [B][L][C], va [B][C][L] (bf16)
// ---------------------------------------------------------------------------
__global__ __launch_bounds__(256)
void cin1_convs(const float* __restrict__ cli,
                const float* __restrict__ akw, const float* __restrict__ akb,
                const float* __restrict__ avw, const float* __restrict__ avb,
                const float* __restrict__ bqw, const float* __restrict__ bqb,
                unsigned short* __restrict__ kTa, unsigned short* __restrict__ va,
                unsigned short* __restrict__ qTb)
{
    const int bz = blockIdx.z;
    const int l0 = blockIdx.x * 64;
    __shared__ float xs[66];
    if (threadIdx.x < 66) {
        const int l = l0 + (int)threadIdx.x - 1;
        xs[threadIdx.x] = (l >= 0 && l < 1024) ? cli[(long)bz * 1024 + l] : 0.f;
    }
    __syncthreads();
    for (int i = threadIdx.x; i < 64 * 256; i += 256) {          // [l][c] outputs
        const int r = i >> 8, c = i & 255;
        const float x0 = xs[r], x1 = xs[r + 1], x2 = xs[r + 2];
        const float kv = akw[c * 3] * x0 + akw[c * 3 + 1] * x1 + akw[c * 3 + 2] * x2 + akb[c];
        const float qv = bqw[c * 3] * x0 + bqw[c * 3 + 1] * x1 + bqw[c * 3 + 2] * x2 + bqb[c];
        const long base = ((long)bz * 1024 + l0 + r) * 256 + c;
        kTa[base] = f2bf(kv);
        qTb[base] = f2bf(qv);
    }
    for (int i = threadIdx.x; i < 64 * 256; i += 256) {          // [c][l] output
        const int c = i >> 6, r = i & 63;
        const float x0 = xs[r], x1 = xs[r + 1], x2 = xs[r + 2];
        const float vv = avw[c * 3] * x0 + avw[c * 3 + 1] * x1 + avw[c * 3 + 2] * x2 + avb[c];
        va[((long)bz * 256 + c) * 1024 + l0 + r] = f2bf(vv);
    }
}

// ---------------------------------------------------------------------------
// Row softmax over 1024 bf16 elements, in place. One block (256 thr) per row.
// ---------------------------------------------------------------------------
__global__ __launch_bounds__(256)
void softmax1024(unsigned short* __restrict__ S)
{
    const long row = blockIdx.x;
    unsigned short* p = S + row * 1024;
    const int t = threadIdx.x;
    ushort4 raw = *(const ushort4*)(p + t * 4);
    float v0 = bf2f(raw.x), v1 = bf2f(raw.y), v2 = bf2f(raw.z), v3 = bf2f(raw.w);
    float m = fmaxf(fmaxf(v0, v1), fmaxf(v2, v3));
#pragma unroll
    for (int off = 32; off; off >>= 1) m = fmaxf(m, __shfl_xor(m, off));
    __shared__ float red[8];
    const int wave = t >> 6, lane = t & 63;
    if (lane == 0) red[wave] = m;
    __syncthreads();
    m = fmaxf(fmaxf(red[0], red[1]), fmaxf(red[2], red[3]));
    v0 = __expf(v0 - m); v1 = __expf(v1 - m); v2 = __expf(v2 - m); v3 = __expf(v3 - m);
    float s = v0 + v1 + v2 + v3;
#pragma unroll
    for (int off = 32; off; off >>= 1) s += __shfl_xor(s, off);
    if (lane == 0) red[4 + wave] = s;
    __syncthreads();
    s = red[4] + red[5] + red[6] + red[7];
    const float inv = 1.f / s;
    ushort4 o;
    o.x = f2bf(v0 * inv); o.y = f2bf(v1 * inv); o.z = f2bf(v2 * inv); o.w = f2bf(v3 * inv);
    *(ushort4*)(p + t * 4) = o;
}

// ---------------------------------------------------------------------------
// BN stats: per channel (512 = 2 branches x 256) over 16x1024 samples.
// ss[ch] = gamma*inv_std ; ss[512+ch] = beta - mean*gamma*inv_std
// ---------------------------------------------------------------------------
__global__ __launch_bounds__(256)
void bn_stats(const float* __restrict__ ya, const float* __restrict__ yb,
              const float* __restrict__ ag, const float* __restrict__ abeta,
              const float* __restrict__ bg, const float* __restrict__ bbeta,
              float* __restrict__ ss)
{
    const int ch = blockIdx.x;
    const float* y = (ch < 256) ? ya : yb;
    const int c = ch & 255;
    const int t = threadIdx.x;
    float s = 0.f, s2 = 0.f;
    for (int idx = t; idx < 16 * 1024; idx += 256) {
        const int b = idx >> 10, l = idx & 1023;
        const float v = y[((long)b * 256 + c) * 1024 + l];
        s += v; s2 += v * v;
    }
#pragma unroll
    for (int off = 32; off; off >>= 1) { s += __shfl_xor(s, off); s2 += __shfl_xor(s2, off); }
    __shared__ float r1[4], r2[4];
    const int wave = t >> 6, lane = t & 63;
    if (lane == 0) { r1[wave] = s; r2[wave] = s2; }
    __syncthreads();
    if (t == 0) {
        s = r1[0] + r1[1] + r1[2] + r1[3];
        s2 = r2[0] + r2[1] + r2[2] + r2[3];
        const float mean = s * (1.f / 16384.f);
        const float var = s2 * (1.f / 16384.f) - mean * mean;   // biased, matches jnp.var
        const float inv = rsqrtf(var + 1e-5f);
        const float g = (ch < 256) ? ag[c] : bg[c];
        const float be = (ch < 256) ? abeta[c] : bbeta[c];
        const float sc = g * inv;
        ss[ch] = sc;
        ss[512 + ch] = be - mean * sc;
    }
}

// out[b][ch][l] = y*scale + shift + image[b][ch&255][l]  (residual = image for BOTH halves)
__global__ __launch_bounds__(256)
void bn_apply(const float* __restrict__ ya, const float* __restrict__ yb,
              const float* __restrict__ img, const float* __restrict__ ss,
              float* __restrict__ out)
{
    const long i4 = (long)blockIdx.x * 256 + threadIdx.x;
    const long e = i4 * 4;
    const int l = (int)(e & 1023);
    const int ch = (int)((e >> 10) & 511);
    const int b = (int)(e >> 19);
    const float* y = (ch < 256) ? ya : yb;
    const int c = ch & 255;
    const float sc = ss[ch], sh = ss[512 + ch];
    const long yoff = ((long)b * 256 + c) * 1024 + l;
    const float4 yv = *(const float4*)(y + yoff);
    const float4 iv = *(const float4*)(img + yoff);
    float4 o;
    o.x = yv.x * sc + sh + iv.x;
    o.y = yv.y * sc + sh + iv.y;
    o.z = yv.z * sc + sh + iv.z;
    o.w = yv.w * sc + sh + iv.w;
    *(float4*)(out + e) = o;
}

// cast 5 weight tensors [256][768] fp32 -> bf16, packed consecutively
__global__ __launch_bounds__(256)
void cast_w(const float* __restrict__ w0, const float* __restrict__ w1,
            const float* __restrict__ w2, const float* __restrict__ w3,
            const float* __restrict__ w4, unsigned short* __restrict__ out)
{
    const int i = blockIdx.x * 256 + threadIdx.x;   // grid sized exactly 5*196608
    const int which = i / 196608, off = i - which * 196608;
    const float* w = (which == 0) ? w0 : (which == 1) ? w1 : (which == 2) ? w2 : (which == 3) ? w3 : w4;
    out[i] = f2bf(w[off]);
}

// ---------------------------------------------------------------------------
extern "C" void kernel_launch(void* const* d_in, const int* in_sizes, int n_in,
                              void* d_out, int out_size, void* d_ws, size_t ws_size,
                              hipStream_t stream)
{
    const float* image    = (const float*)d_in[0];
    const float* clinical = (const float*)d_in[1];
    const float* a_qw = (const float*)d_in[2];  const float* a_qb = (const float*)d_in[3];
    const float* a_kw = (const float*)d_in[4];  const float* a_kb = (const float*)d_in[5];
    const float* a_vw = (const float*)d_in[6];  const float* a_vb = (const float*)d_in[7];
    const float* a_ow = (const float*)d_in[8];  const float* a_ob = (const float*)d_in[9];
    const float* a_g  = (const float*)d_in[10]; const float* a_be = (const float*)d_in[11];
    const float* b_qw = (const float*)d_in[12]; const float* b_qb = (const float*)d_in[13];
    const float* b_kw = (const float*)d_in[14]; const float* b_kb = (const float*)d_in[15];
    const float* b_vw = (const float*)d_in[16]; const float* b_vb = (const float*)d_in[17];
    const float* b_ow = (const float*)d_in[18]; const float* b_ob = (const float*)d_in[19];
    const float* b_g  = (const float*)d_in[20]; const float* b_be = (const float*)d_in[21];
    float* out = (float*)d_out;

    char* ws = (char*)d_ws;
    // workspace layout (~138 MB, buffers reused where lifetimes allow)
    unsigned short* Ximg = (unsigned short*)(ws + 0);           // 24 MB; reused for Xctx
    unsigned short* kTa  = (unsigned short*)(ws + 25165824L);
    unsigned short* va   = (unsigned short*)(ws + 33554432L);
    unsigned short* qTb  = (unsigned short*)(ws + 41943040L);
    unsigned short* qTa  = (unsigned short*)(ws + 50331648L);   // reused for ctx
    unsigned short* kTb  = (unsigned short*)(ws + 58720256L);
    unsigned short* vb   = (unsigned short*)(ws + 67108864L);
    unsigned short* S    = (unsigned short*)(ws + 75497472L);   // 32 MB, reused a then b
    float* ya            = (float*)(ws + 109051904L);
    float* yb            = (float*)(ws + 125829120L);
    float* ss            = (float*)(ws + 142606336L);
    unsigned short* W    = (unsigned short*)(ws + 142610432L);  // 5 x [256][768] bf16
    unsigned short* Wqa = W;
    unsigned short* Wkb = W + 196608;
    unsigned short* Wvb = W + 2 * 196608;
    unsigned short* Woa = W + 3 * 196608;
    unsigned short* Wob = W + 4 * 196608;
    unsigned short* ctx  = qTa;
    unsigned short* Xctx = Ximg;

    const dim3 blk(256);
    const long sImg = 1024L * 768, sQT = 1024L * 256, sV = 256L * 1024, sS = 1024L * 1024;

    cast_w<<<3840, blk, 0, stream>>>(a_qw, b_kw, b_vw, a_ow, b_ow, W);
    im2col3<float><<<dim3(16, 1, 16), blk, 0, stream>>>(image, Ximg);
    cin1_convs<<<dim3(16, 1, 16), blk, 0, stream>>>(clinical, a_kw, a_kb, a_vw, a_vb, b_qw, b_qb,
                                                    kTa, va, qTb);
    // qTa[l][co] = conv(image,Wqa)+qb   (A=Ximg, B=Wqa -> C transposed for free)
    gemm_nt<true><<<dim3(2, 8, 16), blk, 0, stream>>>(Ximg, Wqa, qTa, 768, 768, 768, 256,
                                                      sImg, 0, sQT, 1.f, nullptr, a_qb);
    // kTb[l][co]
    gemm_nt<true><<<dim3(2, 8, 16), blk, 0, stream>>>(Ximg, Wkb, kTb, 768, 768, 768, 256,
                                                      sImg, 0, sQT, 1.f, nullptr, b_kb);
    // vb[co][l]
    gemm_nt<true><<<dim3(8, 2, 16), blk, 0, stream>>>(Wvb, Ximg, vb, 768, 768, 768, 1024,
                                                      0, sImg, sV, 1.f, b_vb, nullptr);
    // ---- branch a ----
    gemm_nt<true><<<dim3(8, 8, 16), blk, 0, stream>>>(qTa, kTa, S, 256, 256, 256, 1024,
                                                      sQT, sQT, sS, 0.0625f, nullptr, nullptr);
    softmax1024<<<16384, blk, 0, stream>>>(S);
    gemm_nt<true><<<dim3(8, 2, 16), blk, 0, stream>>>(va, S, ctx, 1024, 1024, 1024, 1024,
                                                      sV, sS, sV, 1.f, nullptr, nullptr);
    im2col3<unsigned short><<<dim3(16, 1, 16), blk, 0, stream>>>(ctx, Xctx);
    gemm_nt<false><<<dim3(8, 2, 16), blk, 0, stream>>>(Woa, Xctx, ya, 768, 768, 768, 1024,
                                                       0, sImg, sV, 1.f, a_ob, nullptr);
    // ---- branch b ----
    gemm_nt<true><<<dim3(8, 8, 16), blk, 0, stream>>>(qTb, kTb, S, 256, 256, 256, 1024,
                                                      sQT, sQT, sS, 0.0625f, nullptr, nullptr);
    softmax1024<<<16384, blk, 0, stream>>>(S);
    gemm_nt<true><<<dim3(8, 2, 16), blk, 0, stream>>>(vb, S, ctx, 1024, 1024, 1024, 1024,
                                                      sV, sS, sV, 1.f, nullptr, nullptr);
    im2col3<unsigned short><<<dim3(16, 1, 16), blk, 0, stream>>>(ctx, Xctx);
    gemm_nt<false><<<dim3(8, 2, 16), blk, 0, stream>>>(Wob, Xctx, yb, 768, 768, 768, 1024,
                                                       0, sImg, sV, 1.f, b_ob, nullptr);
    // ---- BN + residual + concat ----
    bn_stats<<<512, blk, 0, stream>>>(ya, yb, a_g, a_be, b_g, b_be, ss);
    bn_apply<<<8192, blk, 0, stream>>>(ya, yb, image, ss, out);
}

// Round 3
// 421.144 us; speedup vs baseline: 1.2373x; 1.2373x over previous
//
#include <hip/hip_runtime.h>

// CrossSymmetricModal: two cross-attention branches, all heavy math as bf16 MFMA NT-GEMM.
// B=16, C=256, L=1024.  Output [16][512][1024] fp32.

typedef short bf16x8 __attribute__((ext_vector_type(8)));
typedef float f32x4 __attribute__((ext_vector_type(4)));

__device__ __forceinline__ unsigned short f2bf(float f) {
    union { float f; unsigned u; } v; v.f = f;
    unsigned r = v.u + 0x7fffu + ((v.u >> 16) & 1u);   // RNE
    return (unsigned short)(r >> 16);
}
__device__ __forceinline__ float bf2f(unsigned short h) {
    union { unsigned u; float f; } v; v.u = ((unsigned)h) << 16;
    return v.f;
}
__device__ __forceinline__ float ldval(const float* p) { return *p; }
__device__ __forceinline__ float ldval(const unsigned short* p) { return bf2f(*p); }

// ---------------------------------------------------------------------------
// NT GEMM with 2-way branch batching over blockIdx.z.
// C[i,j] = alpha*sum_k A[i*lda+k]*B[j*ldb+k] + bias_row[i] + bias_col[j]
// zz < zsplit -> op0 batch zz ; else op1 batch zz-zsplit.  C offset uses global zz.
// 128x128 tile, BK=32, 4 waves 2x2, each wave 4x4 of 16x16x32 MFMA.
// LDS rows padded 32->40 elems (80B) => <=2-way bank conflicts (free, m136).
// ---------------------------------------------------------------------------
#define TM 128
#define TN 128
#define BK 32
#define LSTR 40

struct GOp {
    const unsigned short* A; const unsigned short* B;
    long sA, sB; int lda, ldb;
    const float* bias_row; const float* bias_col;
};

template<bool OUT_BF16>
__global__ __launch_bounds__(256)
void gemm_nt(GOp op0, GOp op1, int zsplit,
             void* __restrict__ C, long sC, int ldc, int K, float alpha)
{
    __shared__ unsigned short lA[TM * LSTR];
    __shared__ unsigned short lB[TN * LSTR];
    const int zz = blockIdx.z;
    const bool br = (zz >= zsplit);
    const GOp op = br ? op1 : op0;
    const int bz = br ? zz - zsplit : zz;
    const unsigned short* Ab = op.A + op.sA * bz;
    const unsigned short* Bb = op.B + op.sB * bz;
    const int lda = op.lda, ldb = op.ldb;
    const int i0 = blockIdx.y * TM;
    const int j0 = blockIdx.x * TN;
    const int t = threadIdx.x;
    const int lane = t & 63;
    const int wave = t >> 6;
    const int wm = wave & 1, wn = wave >> 1;
    const int srow = t >> 2, sq = t & 3;           // staging: 4 lanes x 16B per row

    const unsigned short* Ap = Ab + (long)(i0 + srow) * lda + sq * 8;
    const unsigned short* Bp = Bb + (long)(j0 + srow) * ldb + sq * 8;
    const long a64 = (long)64 * lda, b64 = (long)64 * ldb;

    f32x4 acc[4][4];
#pragma unroll
    for (int a_ = 0; a_ < 4; ++a_)
#pragma unroll
        for (int b_ = 0; b_ < 4; ++b_)
            acc[a_][b_] = (f32x4){0.f, 0.f, 0.f, 0.f};

    uint4 pa0 = *(const uint4*)(Ap);
    uint4 pa1 = *(const uint4*)(Ap + a64);
    uint4 pb0 = *(const uint4*)(Bp);
    uint4 pb1 = *(const uint4*)(Bp + b64);

    const int frow = lane & 15;
    const int fk = (lane >> 4) * 8;

    int k0 = 0;
    while (true) {
        __syncthreads();
        *(uint4*)(&lA[srow * LSTR + sq * 8]) = pa0;
        *(uint4*)(&lA[(srow + 64) * LSTR + sq * 8]) = pa1;
        *(uint4*)(&lB[srow * LSTR + sq * 8]) = pb0;
        *(uint4*)(&lB[(srow + 64) * LSTR + sq * 8]) = pb1;
        __syncthreads();
        const bool more = (k0 + BK < K);
        if (more) {
            pa0 = *(const uint4*)(Ap + k0 + BK);
            pa1 = *(const uint4*)(Ap + a64 + k0 + BK);
            pb0 = *(const uint4*)(Bp + k0 + BK);
            pb1 = *(const uint4*)(Bp + b64 + k0 + BK);
        }
        bf16x8 af[4], bfr[4];
#pragma unroll
        for (int mt = 0; mt < 4; ++mt)
            af[mt] = *(const bf16x8*)(&lA[(wm * 64 + mt * 16 + frow) * LSTR + fk]);
#pragma unroll
        for (int nt = 0; nt < 4; ++nt)
            bfr[nt] = *(const bf16x8*)(&lB[(wn * 64 + nt * 16 + frow) * LSTR + fk]);
#pragma unroll
        for (int mt = 0; mt < 4; ++mt)
#pragma unroll
            for (int nt = 0; nt < 4; ++nt)
                acc[mt][nt] = __builtin_amdgcn_mfma_f32_16x16x32_bf16(af[mt], bfr[nt], acc[mt][nt], 0, 0, 0);
        if (!more) break;
        k0 += BK;
    }

    const int lr = (lane >> 4) * 4;   // C/D: row=(lane>>4)*4+reg, col=lane&15 (m89/m91)
    const int lc = lane & 15;
#pragma unroll
    for (int mt = 0; mt < 4; ++mt) {
#pragma unroll
        for (int nt = 0; nt < 4; ++nt) {
            const int col = j0 + wn * 64 + nt * 16 + lc;
            const float bc = op.bias_col ? op.bias_col[col] : 0.f;
#pragma unroll
            for (int r = 0; r < 4; ++r) {
                const int row = i0 + wm * 64 + mt * 16 + lr + r;
                const float brv = op.bias_row ? op.bias_row[row] : 0.f;
                const float val = acc[mt][nt][r] * alpha + brv + bc;
                const long off = sC * zz + (long)row * ldc + col;
                if (OUT_BF16) ((unsigned short*)C)[off] = f2bf(val);
                else          ((float*)C)[off] = val;
            }
        }
    }
}

// ---------------------------------------------------------------------------
// im2col (K=3, pad=1):  x [Z][256][1024] -> xt [Z][1024][768] bf16,
// xt[z][l][ci*3+j] = x[z][ci][l+j-1].  64(l) x 64(ci) tile per block.
// K-offset of this channel sub-tile is ci0*3 (3 taps per channel).
// ---------------------------------------------------------------------------
template<typename T>
__global__ __launch_bounds__(256)
void im2col3(const T* __restrict__ x, unsigned short* __restrict__ xt)
{
    const int z = blockIdx.z;
    const int l0 = blockIdx.x * 64;
    const int ci0 = blockIdx.y * 64;
    __shared__ unsigned short tile[64 * 66];   // [ci_loc][ll], ll = l-l0+1
    const T* xb = x + (long)z * 256 * 1024;
    for (int idx = threadIdx.x; idx < 64 * 66; idx += 256) {
        const int ci = idx / 66, ll = idx - ci * 66;
        const int l = l0 + ll - 1;
        const float v = (l >= 0 && l < 1024) ? ldval(xb + (long)(ci0 + ci) * 1024 + l) : 0.f;
        tile[ci * 66 + ll] = f2bf(v);
    }
    __syncthreads();
    unsigned short* xtb = xt + ((long)z * 1024 + l0) * 768 + ci0 * 3;   // FIX: was ci0*192
    for (int i = threadIdx.x; i < 64 * 24; i += 256) {
        const int r = i / 24, cq = i - r * 24;
        const int kloc = cq * 8;
        union { uint4 u; unsigned short s[8]; } o;
#pragma unroll
        for (int e = 0; e < 8; ++e) {
            const int k = kloc + e;
            const int ci = k / 3, j = k - ci * 3;
            o.s[e] = tile[ci * 66 + r + j];
        }
        *(uint4*)(xtb + (long)r * 768 + kloc) = o.u;
    }
}

// ---------------------------------------------------------------------------
// Cin=1 convs from clinical: kTa [B][L][C], qTb [B][L][C], va [B][C][L] (bf16)
// 32 l-positions per block, grid (32,1,16).
// ---------------------------------------------------------------------------
__global__ __launch_bounds__(256)
void cin1_convs(const float* __restrict__ cli,
                const float* __restrict__ akw, const float* __restrict__ akb,
                const float* __restrict__ avw, const float* __restrict__ avb,
                const float* __restrict__ bqw, const float* __restrict__ bqb,
                unsigned short* __restrict__ kTa, unsigned short* __restrict__ va,
                unsigned short* __restrict__ qTb)
{
    const int bz = blockIdx.z;
    const int l0 = blockIdx.x * 32;
    __shared__ float xs[34];
    if (threadIdx.x < 34) {
        const int l = l0 + (int)threadIdx.x - 1;
        xs[threadIdx.x] = (l >= 0 && l < 1024) ? cli[(long)bz * 1024 + l] : 0.f;
    }
    __syncthreads();
    for (int i = threadIdx.x; i < 32 * 256; i += 256) {          // [l][c] outputs
        const int r = i >> 8, c = i & 255;
        const float x0 = xs[r], x1 = xs[r + 1], x2 = xs[r + 2];
        const float kv = akw[c * 3] * x0 + akw[c * 3 + 1] * x1 + akw[c * 3 + 2] * x2 + akb[c];
        const float qv = bqw[c * 3] * x0 + bqw[c * 3 + 1] * x1 + bqw[c * 3 + 2] * x2 + bqb[c];
        const long base = ((long)bz * 1024 + l0 + r) * 256 + c;
        kTa[base] = f2bf(kv);
        qTb[base] = f2bf(qv);
    }
    for (int i = threadIdx.x; i < 32 * 256; i += 256) {          // [c][l] output
        const int c = i >> 5, r = i & 31;
        const float x0 = xs[r], x1 = xs[r + 1], x2 = xs[r + 2];
        const float vv = avw[c * 3] * x0 + avw[c * 3 + 1] * x1 + avw[c * 3 + 2] * x2 + avb[c];
        va[((long)bz * 256 + c) * 1024 + l0 + r] = f2bf(vv);
    }
}

// ---------------------------------------------------------------------------
// Row softmax over 1024 bf16 elements, in place. One block (256 thr) per row.
// ---------------------------------------------------------------------------
__global__ __launch_bounds__(256)
void softmax1024(unsigned short* __restrict__ S)
{
    const long row = blockIdx.x;
    unsigned short* p = S + row * 1024;
    const int t = threadIdx.x;
    ushort4 raw = *(const ushort4*)(p + t * 4);
    float v0 = bf2f(raw.x), v1 = bf2f(raw.y), v2 = bf2f(raw.z), v3 = bf2f(raw.w);
    float m = fmaxf(fmaxf(v0, v1), fmaxf(v2, v3));
#pragma unroll
    for (int off = 32; off; off >>= 1) m = fmaxf(m, __shfl_xor(m, off));
    __shared__ float red[8];
    const int wave = t >> 6, lane = t & 63;
    if (lane == 0) red[wave] = m;
    __syncthreads();
    m = fmaxf(fmaxf(red[0], red[1]), fmaxf(red[2], red[3]));
    v0 = __expf(v0 - m); v1 = __expf(v1 - m); v2 = __expf(v2 - m); v3 = __expf(v3 - m);
    float s = v0 + v1 + v2 + v3;
#pragma unroll
    for (int off = 32; off; off >>= 1) s += __shfl_xor(s, off);
    if (lane == 0) red[4 + wave] = s;
    __syncthreads();
    s = red[4] + red[5] + red[6] + red[7];
    const float inv = 1.f / s;
    ushort4 o;
    o.x = f2bf(v0 * inv); o.y = f2bf(v1 * inv); o.z = f2bf(v2 * inv); o.w = f2bf(v3 * inv);
    *(ushort4*)(p + t * 4) = o;
}

// ---------------------------------------------------------------------------
// BN stats over Y [32][256][1024] (z: 0..15 branch a, 16..31 branch b).
// ss[ch] = gamma*inv_std ; ss[512+ch] = beta - mean*gamma*inv_std, ch=branch*256+c
// ---------------------------------------------------------------------------
__global__ __launch_bounds__(256)
void bn_stats(const float* __restrict__ Y,
              const float* __restrict__ ag, const float* __restrict__ abeta,
              const float* __restrict__ bg, const float* __restrict__ bbeta,
              float* __restrict__ ss)
{
    const int ch = blockIdx.x;
    const int branch = ch >> 8, c = ch & 255;
    const int t = threadIdx.x;
    float s = 0.f, s2 = 0.f;
    for (int idx = t; idx < 16 * 1024; idx += 256) {
        const int b = idx >> 10, l = idx & 1023;
        const float v = Y[(((long)(branch * 16 + b)) * 256 + c) * 1024 + l];
        s += v; s2 += v * v;
    }
#pragma unroll
    for (int off = 32; off; off >>= 1) { s += __shfl_xor(s, off); s2 += __shfl_xor(s2, off); }
    __shared__ float r1[4], r2[4];
    const int wave = t >> 6, lane = t & 63;
    if (lane == 0) { r1[wave] = s; r2[wave] = s2; }
    __syncthreads();
    if (t == 0) {
        s = r1[0] + r1[1] + r1[2] + r1[3];
        s2 = r2[0] + r2[1] + r2[2] + r2[3];
        const float mean = s * (1.f / 16384.f);
        const float var = s2 * (1.f / 16384.f) - mean * mean;   // biased, matches jnp.var
        const float inv = rsqrtf(var + 1e-5f);
        const float g = branch ? bg[c] : ag[c];
        const float be = branch ? bbeta[c] : abeta[c];
        const float sc = g * inv;
        ss[ch] = sc;
        ss[512 + ch] = be - mean * sc;
    }
}

// out[b][ch][l] = y*scale + shift + image[b][ch&255][l]  (residual = image for BOTH halves)
__global__ __launch_bounds__(256)
void bn_apply(const float* __restrict__ Y, const float* __restrict__ img,
              const float* __restrict__ ss, float* __restrict__ out)
{
    const long i4 = (long)blockIdx.x * 256 + threadIdx.x;
    const long e = i4 * 4;
    const int l = (int)(e & 1023);
    const int ch = (int)((e >> 10) & 511);
    const int b = (int)(e >> 19);
    const int branch = ch >> 8, c = ch & 255;
    const float sc = ss[ch], sh = ss[512 + ch];
    const long yoff = (((long)(branch * 16 + b)) * 256 + c) * 1024 + l;
    const long ioff = ((long)b * 256 + c) * 1024 + l;
    const float4 yv = *(const float4*)(Y + yoff);
    const float4 iv = *(const float4*)(img + ioff);
    float4 o;
    o.x = yv.x * sc + sh + iv.x;
    o.y = yv.y * sc + sh + iv.y;
    o.z = yv.z * sc + sh + iv.z;
    o.w = yv.w * sc + sh + iv.w;
    *(float4*)(out + e) = o;
}

// cast 5 weight tensors [256][768] fp32 -> bf16, packed consecutively:
// order (a_qw, b_kw, b_vw, a_ow, b_ow) so [a_qw;b_kw] is a contiguous [512][768] stack.
__global__ __launch_bounds__(256)
void cast_w(const float* __restrict__ w0, const float* __restrict__ w1,
            const float* __restrict__ w2, const float* __restrict__ w3,
            const float* __restrict__ w4, unsigned short* __restrict__ out)
{
    const int i = blockIdx.x * 256 + threadIdx.x;   // grid sized exactly 5*196608
    const int which = i / 196608, off = i - which * 196608;
    const float* w = (which == 0) ? w0 : (which == 1) ? w1 : (which == 2) ? w2 : (which == 3) ? w3 : w4;
    out[i] = f2bf(w[off]);
}

__global__ __launch_bounds__(256)
void pack_qkb(const float* __restrict__ a_qb, const float* __restrict__ b_kb,
              float* __restrict__ qkb)
{
    const int i = blockIdx.x * 256 + threadIdx.x;   // grid 2 blocks
    qkb[i] = (i < 256) ? a_qb[i] : b_kb[i - 256];
}

// ---------------------------------------------------------------------------
extern "C" void kernel_launch(void* const* d_in, const int* in_sizes, int n_in,
                              void* d_out, int out_size, void* d_ws, size_t ws_size,
                              hipStream_t stream)
{
    const float* image    = (const float*)d_in[0];
    const float* clinical = (const float*)d_in[1];
    const float* a_qw = (const float*)d_in[2];  const float* a_qb = (const float*)d_in[3];
    const float* a_kw = (const float*)d_in[4];  const float* a_kb = (const float*)d_in[5];
    const float* a_vw = (const float*)d_in[6];  const float* a_vb = (const float*)d_in[7];
    const float* a_ow = (const float*)d_in[8];  const float* a_ob = (const float*)d_in[9];
    const float* a_g  = (const float*)d_in[10]; const float* a_be = (const float*)d_in[11];
    const float* b_qw = (const float*)d_in[12]; const float* b_qb = (const float*)d_in[13];
    const float* b_kw = (const float*)d_in[14]; const float* b_kb = (const float*)d_in[15];
    const float* b_vw = (const float*)d_in[16]; const float* b_vb = (const float*)d_in[17];
    const float* b_ow = (const float*)d_in[18]; const float* b_ob = (const float*)d_in[19];
    const float* b_g  = (const float*)d_in[20]; const float* b_be = (const float*)d_in[21];
    float* out = (float*)d_out;

    char* ws = (char*)d_ws;
    const long MB = 1048576L;
    // Layout (overlays exploit lifetimes; peak ~122 MB):
    //  [0..48M)    Ximg [16][1024][768] bf16 (24M) + QK [16][1024][512] bf16 (16M, @24M)
    //              + kTa [16][1024][256] bf16 (8M, @40M); later ALL reused as
    //              Xctx [32][1024][768] bf16 (48M)
    //  [48..56M)   qTb [16][1024][256] bf16
    //  [56..64M)   va  [16][256][1024] bf16
    //  [64..72M)   vb  [16][256][1024] bf16
    //  [72..104M)  S   [16][1024][1024] bf16 (a then b); later Y [32][256][1024] f32
    //  [104..120M) ctx [32][256][1024] bf16
    //  [120M..)    W (5x196608 bf16), qkb (512 f32), ss (1024 f32)
    unsigned short* Ximg = (unsigned short*)(ws);
    unsigned short* QK   = (unsigned short*)(ws + 24 * MB);
    unsigned short* kTa  = (unsigned short*)(ws + 40 * MB);
    unsigned short* Xctx = (unsigned short*)(ws);
    unsigned short* qTb  = (unsigned short*)(ws + 48 * MB);
    unsigned short* va   = (unsigned short*)(ws + 56 * MB);
    unsigned short* vb   = (unsigned short*)(ws + 64 * MB);
    unsigned short* S    = (unsigned short*)(ws + 72 * MB);
    float*          Y    = (float*)(ws + 72 * MB);
    unsigned short* ctx  = (unsigned short*)(ws + 104 * MB);
    unsigned short* W    = (unsigned short*)(ws + 120 * MB);
    float*          qkb  = (float*)(ws + 120 * MB + 1966080L);   // right after W (5*196608*2 B)
    float*          ss   = qkb + 512;
    unsigned short* Wvb = W + 2 * 196608;
    unsigned short* Woa = W + 3 * 196608;
    unsigned short* Wob = W + 4 * 196608;

    const dim3 blk(256);
    const long sImg = 1024L * 768, sQK = 1024L * 512, sQT = 1024L * 256,
               sV = 256L * 1024, sS = 1024L * 1024;

    cast_w<<<3840, blk, 0, stream>>>(a_qw, b_kw, b_vw, a_ow, b_ow, W);
    pack_qkb<<<2, blk, 0, stream>>>(a_qb, b_kb, qkb);
    im2col3<float><<<dim3(16, 4, 16), blk, 0, stream>>>(image, Ximg);
    cin1_convs<<<dim3(32, 1, 16), blk, 0, stream>>>(clinical, a_kw, a_kb, a_vw, a_vb, b_qw, b_qb,
                                                    kTa, va, qTb);
    // QK[l][co2] = conv(image,[Wqa;Wkb]) + [a_qb;b_kb]   (M=1024, N=512, K=768)
    {
        GOp op = {Ximg, W, sImg, 0, 768, 768, nullptr, qkb};
        gemm_nt<true><<<dim3(4, 8, 16), blk, 0, stream>>>(op, op, 1000, QK, sQK, 512, 768, 1.f);
    }
    // vb[co][l]  (M=256, N=1024, K=768)
    {
        GOp op = {Wvb, Ximg, 0, sImg, 768, 768, b_vb, nullptr};
        gemm_nt<true><<<dim3(8, 2, 16), blk, 0, stream>>>(op, op, 1000, vb, sV, 1024, 768, 1.f);
    }
    // ---- branch a: scores/softmax/ctx ----
    {
        GOp op = {QK, kTa, sQK, sQT, 512, 256, nullptr, nullptr};   // qTa = QK cols 0..255
        gemm_nt<true><<<dim3(8, 8, 16), blk, 0, stream>>>(op, op, 1000, S, sS, 1024, 256, 0.0625f);
    }
    softmax1024<<<16384, blk, 0, stream>>>(S);
    {
        GOp op = {va, S, sV, sS, 1024, 1024, nullptr, nullptr};
        gemm_nt<true><<<dim3(8, 2, 16), blk, 0, stream>>>(op, op, 1000, ctx, sV, 1024, 1024, 1.f);
    }
    // ---- branch b: scores/softmax/ctx ----
    {
        GOp op = {qTb, QK + 256, sQT, sQK, 256, 512, nullptr, nullptr};  // kTb = QK cols 256..511
        gemm_nt<true><<<dim3(8, 8, 16), blk, 0, stream>>>(op, op, 1000, S, sS, 1024, 256, 0.0625f);
    }
    softmax1024<<<16384, blk, 0, stream>>>(S);
    {
        GOp op = {vb, S, sV, sS, 1024, 1024, nullptr, nullptr};
        gemm_nt<true><<<dim3(8, 2, 16), blk, 0, stream>>>(op, op, 1000,
                                                          ctx + 16 * sV, sV, 1024, 1024, 1.f);
    }
    // ---- both branches batched: im2col + o-conv ----
    im2col3<unsigned short><<<dim3(16, 4, 32), blk, 0, stream>>>(ctx, Xctx);
    {
        GOp opA = {Woa, Xctx, 0, sImg, 768, 768, a_ob, nullptr};
        GOp opB = {Wob, Xctx + 16 * sImg, 0, sImg, 768, 768, b_ob, nullptr};
        gemm_nt<false><<<dim3(8, 2, 32), blk, 0, stream>>>(opA, opB, 16, Y, sV, 1024, 768, 1.f);
    }
    // ---- BN + residual + concat ----
    bn_stats<<<512, blk, 0, stream>>>(Y, a_g, a_be, b_g, b_be, ss);
    bn_apply<<<8192, blk, 0, stream>>>(Y, image, ss, out);
}

// Round 4
// 369.677 us; speedup vs baseline: 1.4096x; 1.1392x over previous
//
#include <hip/hip_runtime.h>

// CrossSymmetricModal: two cross-attention branches. B=16, C=256, L=1024.
// All convs are NT-GEMMs over a padded transposed activation with tap-major K:
//   im2col row l == xT_pad + l*256, 768 consecutive elems (overlapping windows).
// Output [16][512][1024] fp32.

typedef short bf16x8 __attribute__((ext_vector_type(8)));
typedef float f32x4 __attribute__((ext_vector_type(4)));

__device__ __forceinline__ unsigned short f2bf(float f) {
    union { float f; unsigned u; } v; v.f = f;
    unsigned r = v.u + 0x7fffu + ((v.u >> 16) & 1u);   // RNE
    return (unsigned short)(r >> 16);
}
__device__ __forceinline__ float bf2f(unsigned short h) {
    union { unsigned u; float f; } v; v.u = ((unsigned)h) << 16;
    return v.f;
}

// ---------------------------------------------------------------------------
// NT GEMM, 2-op batched over blockIdx.z.
// C[i,j] = alpha*sum_k A[i*lda+k]*B[j*ldb+k] + bias_row[i] + bias_col[j]
// 128x128 tile, BK=32, 4 waves 2x2, each wave 4x4 of 16x16x32 MFMA.
// LDS rows padded to 40 elems (80B) => <=2-way bank conflicts (free, m136).
// Per-op tile counts (nxt,nyt) allow merging different-shaped GEMMs; excess
// blocks exit before any barrier.
// ---------------------------------------------------------------------------
#define TM 128
#define TN 128
#define BK 32
#define LSTR 40

struct GOp {
    const unsigned short* A; const unsigned short* B; void* C;
    long sA, sB, sC;
    int lda, ldb, ldc, nxt, nyt;
    const float* bias_row; const float* bias_col;
};

template<bool OUT_BF16>
__global__ __launch_bounds__(256)
void gemm_nt(GOp op0, GOp op1, int zsplit, int K, float alpha)
{
    __shared__ unsigned short lA[TM * LSTR];
    __shared__ unsigned short lB[TN * LSTR];
    const int zz = blockIdx.z;
    const bool brn = (zz >= zsplit);
    const GOp op = brn ? op1 : op0;
    const int bz = brn ? zz - zsplit : zz;
    if ((int)blockIdx.x >= op.nxt || (int)blockIdx.y >= op.nyt) return;
    const unsigned short* Ab = op.A + op.sA * bz;
    const unsigned short* Bb = op.B + op.sB * bz;
    const int lda = op.lda, ldb = op.ldb;
    const int i0 = blockIdx.y * TM;
    const int j0 = blockIdx.x * TN;
    const int t = threadIdx.x;
    const int lane = t & 63;
    const int wave = t >> 6;
    const int wm = wave & 1, wn = wave >> 1;
    const int srow = t >> 2, sq = t & 3;           // staging: 4 lanes x 16B per row

    const unsigned short* Ap = Ab + (long)(i0 + srow) * lda + sq * 8;
    const unsigned short* Bp = Bb + (long)(j0 + srow) * ldb + sq * 8;
    const long a64 = (long)64 * lda, b64 = (long)64 * ldb;

    f32x4 acc[4][4];
#pragma unroll
    for (int a_ = 0; a_ < 4; ++a_)
#pragma unroll
        for (int b_ = 0; b_ < 4; ++b_)
            acc[a_][b_] = (f32x4){0.f, 0.f, 0.f, 0.f};

    uint4 pa0 = *(const uint4*)(Ap);
    uint4 pa1 = *(const uint4*)(Ap + a64);
    uint4 pb0 = *(const uint4*)(Bp);
    uint4 pb1 = *(const uint4*)(Bp + b64);

    const int frow = lane & 15;
    const int fk = (lane >> 4) * 8;

    int k0 = 0;
    while (true) {
        __syncthreads();
        *(uint4*)(&lA[srow * LSTR + sq * 8]) = pa0;
        *(uint4*)(&lA[(srow + 64) * LSTR + sq * 8]) = pa1;
        *(uint4*)(&lB[srow * LSTR + sq * 8]) = pb0;
        *(uint4*)(&lB[(srow + 64) * LSTR + sq * 8]) = pb1;
        __syncthreads();
        const bool more = (k0 + BK < K);
        if (more) {
            pa0 = *(const uint4*)(Ap + k0 + BK);
            pa1 = *(const uint4*)(Ap + a64 + k0 + BK);
            pb0 = *(const uint4*)(Bp + k0 + BK);
            pb1 = *(const uint4*)(Bp + b64 + k0 + BK);
        }
        bf16x8 af[4], bfr[4];
#pragma unroll
        for (int mt = 0; mt < 4; ++mt)
            af[mt] = *(const bf16x8*)(&lA[(wm * 64 + mt * 16 + frow) * LSTR + fk]);
#pragma unroll
        for (int nt = 0; nt < 4; ++nt)
            bfr[nt] = *(const bf16x8*)(&lB[(wn * 64 + nt * 16 + frow) * LSTR + fk]);
#pragma unroll
        for (int mt = 0; mt < 4; ++mt)
#pragma unroll
            for (int nt = 0; nt < 4; ++nt)
                acc[mt][nt] = __builtin_amdgcn_mfma_f32_16x16x32_bf16(af[mt], bfr[nt], acc[mt][nt], 0, 0, 0);
        if (!more) break;
        k0 += BK;
    }

    const int lr = (lane >> 4) * 4;   // C/D: row=(lane>>4)*4+reg, col=lane&15 (m89/m91)
    const int lc = lane & 15;
#pragma unroll
    for (int mt = 0; mt < 4; ++mt) {
#pragma unroll
        for (int nt = 0; nt < 4; ++nt) {
            const int col = j0 + wn * 64 + nt * 16 + lc;
            const float bc = op.bias_col ? op.bias_col[col] : 0.f;
#pragma unroll
            for (int r = 0; r < 4; ++r) {
                const int row = i0 + wm * 64 + mt * 16 + lr + r;
                const float brv = op.bias_row ? op.bias_row[row] : 0.f;
                const float val = acc[mt][nt][r] * alpha + brv + bc;
                const long off = op.sC * bz + (long)row * op.ldc + col;
                if (OUT_BF16) ((unsigned short*)op.C)[off] = f2bf(val);
                else          ((float*)op.C)[off] = val;
            }
        }
    }
}

// ---------------------------------------------------------------------------
// Fused prep: range-dispatched over blockIdx.x (grid 5474):
//  [0,1024)    image [16][256][1024] f32 -> imgT_pad [16][1026][256] bf16 (rows+1)
//  [1024,1536) cin1 convs from clinical: kTa/qTb [16][1024][256], va [16][256][1024]
//  [1536,5376) weight repack tap-major: W'[row][j*256+ci] = w[row&255][ci*3+j], bf16
//              rows: 0-255 a_qw | 256-511 b_kw | 512-767 b_vw | 768-1023 a_ow | 1024-1279 b_ow
//  [5376,5474) qkb bias pack (512 f32) + zero pad rows of imgT_pad (8192) & ctxT_pad (16384)
// ---------------------------------------------------------------------------
__global__ __launch_bounds__(256)
void prep(const float* __restrict__ image, const float* __restrict__ cli,
          const float* __restrict__ a_qw, const float* __restrict__ a_qb,
          const float* __restrict__ a_kw, const float* __restrict__ a_kb,
          const float* __restrict__ a_vw, const float* __restrict__ a_vb,
          const float* __restrict__ a_ow,
          const float* __restrict__ b_qw, const float* __restrict__ b_qb,
          const float* __restrict__ b_kw, const float* __restrict__ b_kb,
          const float* __restrict__ b_vw, const float* __restrict__ b_vb,
          const float* __restrict__ b_ow,
          unsigned short* __restrict__ imgT, unsigned short* __restrict__ ctxT,
          unsigned short* __restrict__ kTa, unsigned short* __restrict__ va,
          unsigned short* __restrict__ qTb,
          unsigned short* __restrict__ W, float* __restrict__ qkb)
{
    __shared__ char smem[64 * 65 * 4];
    const int b = blockIdx.x;
    const int t = threadIdx.x;
    if (b < 1024) {
        // transpose-cast image tile: 64(l) x 64(c)
        float* tile = (float*)smem;                      // [64][65]
        const int bt = b >> 6, rem = b & 63;
        const int l0 = (rem & 15) * 64, c0 = (rem >> 4) * 64;
        const float* xb = image + ((long)bt * 256 + c0) * 1024 + l0;
        for (int idx = t; idx < 4096; idx += 256) {
            const int cc = idx >> 6, ll = idx & 63;
            tile[cc * 65 + ll] = xb[(long)cc * 1024 + ll];
        }
        __syncthreads();
        unsigned short* op = imgT + ((long)bt * 1026 + l0 + 1) * 256 + c0;
        for (int idx = t; idx < 4096; idx += 256) {
            const int ll = idx >> 6, cc = idx & 63;
            op[(long)ll * 256 + cc] = f2bf(tile[cc * 65 + ll]);
        }
    } else if (b < 1536) {
        // cin1 convs, 32 l-positions per block
        float* xs = (float*)smem;                        // [34]
        const int local = b - 1024;
        const int bz = local >> 5;
        const int l0 = (local & 31) * 32;
        if (t < 34) {
            const int l = l0 + t - 1;
            xs[t] = (l >= 0 && l < 1024) ? cli[(long)bz * 1024 + l] : 0.f;
        }
        __syncthreads();
        for (int i = t; i < 32 * 256; i += 256) {        // [l][c] outputs
            const int r = i >> 8, c = i & 255;
            const float x0 = xs[r], x1 = xs[r + 1], x2 = xs[r + 2];
            const float kv = a_kw[c * 3] * x0 + a_kw[c * 3 + 1] * x1 + a_kw[c * 3 + 2] * x2 + a_kb[c];
            const float qv = b_qw[c * 3] * x0 + b_qw[c * 3 + 1] * x1 + b_qw[c * 3 + 2] * x2 + b_qb[c];
            const long base = ((long)bz * 1024 + l0 + r) * 256 + c;
            kTa[base] = f2bf(kv);
            qTb[base] = f2bf(qv);
        }
        for (int i = t; i < 32 * 256; i += 256) {        // [c][l] output
            const int c = i >> 5, r = i & 31;
            const float x0 = xs[r], x1 = xs[r + 1], x2 = xs[r + 2];
            const float vv = a_vw[c * 3] * x0 + a_vw[c * 3 + 1] * x1 + a_vw[c * 3 + 2] * x2 + a_vb[c];
            va[((long)bz * 256 + c) * 1024 + l0 + r] = f2bf(vv);
        }
    } else if (b < 5376) {
        const int i = (b - 1536) * 256 + t;              // 0..983039
        const int row = i / 768;
        const int kk = i - row * 768;
        const int j = kk >> 8, ci = kk & 255;
        const float* src = (row < 256) ? a_qw : (row < 512) ? b_kw
                         : (row < 768) ? b_vw : (row < 1024) ? a_ow : b_ow;
        const int r = row & 255;
        W[i] = f2bf(src[r * 768 + ci * 3 + j]);
    } else {
        const int i = (b - 5376) * 256 + t;              // 0..25087
        if (i < 512) {
            qkb[i] = (i < 256) ? a_qb[i] : b_kb[i - 256];
        } else if (i < 512 + 8192) {
            const int p = i - 512;                       // imgT pad rows
            const int bi = p >> 9, rr = (p >> 8) & 1, c = p & 255;
            imgT[((long)bi * 1026 + (rr ? 1025 : 0)) * 256 + c] = 0;
        } else {
            const int p = i - 512 - 8192;                // ctxT pad rows
            const int bz = p >> 9, rr = (p >> 8) & 1, c = p & 255;
            ctxT[((long)bz * 1026 + (rr ? 1025 : 0)) * 256 + c] = 0;
        }
    }
}

// ---------------------------------------------------------------------------
// Row softmax over 1024 bf16 elements, in place. One block (256 thr) per row.
// ---------------------------------------------------------------------------
__global__ __launch_bounds__(256)
void softmax1024(unsigned short* __restrict__ S)
{
    const long row = blockIdx.x;
    unsigned short* p = S + row * 1024;
    const int t = threadIdx.x;
    ushort4 raw = *(const ushort4*)(p + t * 4);
    float v0 = bf2f(raw.x), v1 = bf2f(raw.y), v2 = bf2f(raw.z), v3 = bf2f(raw.w);
    float m = fmaxf(fmaxf(v0, v1), fmaxf(v2, v3));
#pragma unroll
    for (int off = 32; off; off >>= 1) m = fmaxf(m, __shfl_xor(m, off));
    __shared__ float red[8];
    const int wave = t >> 6, lane = t & 63;
    if (lane == 0) red[wave] = m;
    __syncthreads();
    m = fmaxf(fmaxf(red[0], red[1]), fmaxf(red[2], red[3]));
    v0 = __expf(v0 - m); v1 = __expf(v1 - m); v2 = __expf(v2 - m); v3 = __expf(v3 - m);
    float s = v0 + v1 + v2 + v3;
#pragma unroll
    for (int off = 32; off; off >>= 1) s += __shfl_xor(s, off);
    if (lane == 0) red[4 + wave] = s;
    __syncthreads();
    s = red[4] + red[5] + red[6] + red[7];
    const float inv = 1.f / s;
    ushort4 o;
    o.x = f2bf(v0 * inv); o.y = f2bf(v1 * inv); o.z = f2bf(v2 * inv); o.w = f2bf(v3 * inv);
    *(ushort4*)(p + t * 4) = o;
}

// ---------------------------------------------------------------------------
// BN stats over Y [32][256][1024] f32 (z: 0..15 branch a, 16..31 branch b).
// ss[ch] = gamma*inv_std ; ss[512+ch] = beta - mean*gamma*inv_std
// ---------------------------------------------------------------------------
__global__ __launch_bounds__(256)
void bn_stats(const float* __restrict__ Y,
              const float* __restrict__ ag, const float* __restrict__ abeta,
              const float* __restrict__ bg, const float* __restrict__ bbeta,
              float* __restrict__ ss)
{
    const int ch = blockIdx.x;
    const int branch = ch >> 8, c = ch & 255;
    const int t = threadIdx.x;
    float s = 0.f, s2 = 0.f;
    for (int idx = t; idx < 16 * 1024; idx += 256) {
        const int b = idx >> 10, l = idx & 1023;
        const float v = Y[(((long)(branch * 16 + b)) * 256 + c) * 1024 + l];
        s += v; s2 += v * v;
    }
#pragma unroll
    for (int off = 32; off; off >>= 1) { s += __shfl_xor(s, off); s2 += __shfl_xor(s2, off); }
    __shared__ float r1[4], r2[4];
    const int wave = t >> 6, lane = t & 63;
    if (lane == 0) { r1[wave] = s; r2[wave] = s2; }
    __syncthreads();
    if (t == 0) {
        s = r1[0] + r1[1] + r1[2] + r1[3];
        s2 = r2[0] + r2[1] + r2[2] + r2[3];
        const float mean = s * (1.f / 16384.f);
        const float var = s2 * (1.f / 16384.f) - mean * mean;   // biased, matches jnp.var
        const float inv = rsqrtf(var + 1e-5f);
        const float g = branch ? bg[c] : ag[c];
        const float be = branch ? bbeta[c] : abeta[c];
        const float sc = g * inv;
        ss[ch] = sc;
        ss[512 + ch] = be - mean * sc;
    }
}

// out[b][ch][l] = y*scale + shift + image[b][ch&255][l]  (residual = image for BOTH halves)
__global__ __launch_bounds__(256)
void bn_apply(const float* __restrict__ Y, const float* __restrict__ img,
              const float* __restrict__ ss, float* __restrict__ out)
{
    const long i4 = (long)blockIdx.x * 256 + threadIdx.x;
    const long e = i4 * 4;
    const int l = (int)(e & 1023);
    const int ch = (int)((e >> 10) & 511);
    const int b = (int)(e >> 19);
    const int branch = ch >> 8, c = ch & 255;
    const float sc = ss[ch], sh = ss[512 + ch];
    const long yoff = (((long)(branch * 16 + b)) * 256 + c) * 1024 + l;
    const long ioff = ((long)b * 256 + c) * 1024 + l;
    const float4 yv = *(const float4*)(Y + yoff);
    const float4 iv = *(const float4*)(img + ioff);
    float4 o;
    o.x = yv.x * sc + sh + iv.x;
    o.y = yv.y * sc + sh + iv.y;
    o.z = yv.z * sc + sh + iv.z;
    o.w = yv.w * sc + sh + iv.w;
    *(float4*)(out + e) = o;
}

// ---------------------------------------------------------------------------
extern "C" void kernel_launch(void* const* d_in, const int* in_sizes, int n_in,
                              void* d_out, int out_size, void* d_ws, size_t ws_size,
                              hipStream_t stream)
{
    const float* image    = (const float*)d_in[0];
    const float* clinical = (const float*)d_in[1];
    const float* a_qw = (const float*)d_in[2];  const float* a_qb = (const float*)d_in[3];
    const float* a_kw = (const float*)d_in[4];  const float* a_kb = (const float*)d_in[5];
    const float* a_vw = (const float*)d_in[6];  const float* a_vb = (const float*)d_in[7];
    const float* a_ow = (const float*)d_in[8];  const float* a_ob = (const float*)d_in[9];
    const float* a_g  = (const float*)d_in[10]; const float* a_be = (const float*)d_in[11];
    const float* b_qw = (const float*)d_in[12]; const float* b_qb = (const float*)d_in[13];
    const float* b_kw = (const float*)d_in[14]; const float* b_kb = (const float*)d_in[15];
    const float* b_vw = (const float*)d_in[16]; const float* b_vb = (const float*)d_in[17];
    const float* b_ow = (const float*)d_in[18]; const float* b_ob = (const float*)d_in[19];
    const float* b_g  = (const float*)d_in[20]; const float* b_be = (const float*)d_in[21];
    float* out = (float*)d_out;

    char* ws = (char*)d_ws;
    const long MB = 1048576L;
    // Workspace (~185 MB):
    unsigned short* imgT = (unsigned short*)(ws);              // [16][1026][256] bf16
    unsigned short* ctxT = (unsigned short*)(ws + 9 * MB);     // [32][1026][256] bf16
    unsigned short* kTa  = (unsigned short*)(ws + 27 * MB);    // [16][1024][256]
    unsigned short* qTb  = (unsigned short*)(ws + 36 * MB);
    unsigned short* va   = (unsigned short*)(ws + 46 * MB);    // [16][256][1024]
    unsigned short* vb   = (unsigned short*)(ws + 54 * MB);
    unsigned short* QK   = (unsigned short*)(ws + 62 * MB);    // [16][1024][512]
    unsigned short* S    = (unsigned short*)(ws + 78 * MB);    // [32][1024][1024]
    float*          Y    = (float*)(ws + 142 * MB);            // [32][256][1024] f32
    unsigned short* W    = (unsigned short*)(ws + 174 * MB);   // [1280][768] bf16 tap-major
    float*          qkb  = (float*)(ws + 176 * MB);
    float*          ss   = qkb + 512;
    unsigned short* Wqk = W;                 // rows 0..511  (a_qw ; b_kw)
    unsigned short* Wvb = W + 512L * 768;
    unsigned short* Woa = W + 768L * 768;
    unsigned short* Wob = W + 1024L * 768;

    const dim3 blk(256);
    const long sIT = 1026L * 256, sQK = 1024L * 512, sQT = 1024L * 256,
               sV = 256L * 1024, sS = 1024L * 1024;

    prep<<<5474, blk, 0, stream>>>(image, clinical,
                                   a_qw, a_qb, a_kw, a_kb, a_vw, a_vb, a_ow,
                                   b_qw, b_qb, b_kw, b_kb, b_vw, b_vb, b_ow,
                                   imgT, ctxT, kTa, va, qTb, W, qkb);
    // Dispatch 2 (merged): QK[l][co2] (z 0..15) + vb[co][l] (z 16..31), K=768
    {
        GOp opQ = {imgT, Wqk, QK, sIT, 0, sQK, 256, 768, 512, 4, 8, nullptr, qkb};
        GOp opV = {Wvb, imgT, vb, 0, sIT, sV, 768, 256, 1024, 8, 2, b_vb, nullptr};
        gemm_nt<true><<<dim3(8, 8, 32), blk, 0, stream>>>(opQ, opV, 16, 768, 1.f);
    }
    // Dispatch 3: scores both branches, K=256, alpha=1/16
    {
        GOp opA = {QK, kTa, S, sQK, sQT, sS, 512, 256, 1024, 8, 8, nullptr, nullptr};
        GOp opB = {qTb, QK + 256, S + 16 * sS, sQT, sQK, sS, 256, 512, 1024, 8, 8, nullptr, nullptr};
        gemm_nt<true><<<dim3(8, 8, 32), blk, 0, stream>>>(opA, opB, 16, 256, 0.0625f);
    }
    softmax1024<<<32768, blk, 0, stream>>>(S);
    // Dispatch 5: ctxT[l][c] both branches (into padded layout, +1 row), K=1024
    {
        GOp opA = {S, va, ctxT + 256, sS, sV, sIT, 1024, 1024, 256, 2, 8, nullptr, nullptr};
        GOp opB = {S + 16 * sS, vb, ctxT + 16 * sIT + 256, sS, sV, sIT, 1024, 1024, 256, 2, 8, nullptr, nullptr};
        gemm_nt<true><<<dim3(2, 8, 32), blk, 0, stream>>>(opA, opB, 16, 1024, 1.f);
    }
    // Dispatch 6: o-conv both branches: Y[co][l] f32, K=768 (window over ctxT)
    {
        GOp opA = {Woa, ctxT, Y, 0, sIT, sV, 768, 256, 1024, 8, 2, a_ob, nullptr};
        GOp opB = {Wob, ctxT + 16 * sIT, Y + 16 * sV, 0, sIT, sV, 768, 256, 1024, 8, 2, b_ob, nullptr};
        gemm_nt<false><<<dim3(8, 2, 32), blk, 0, stream>>>(opA, opB, 16, 768, 1.f);
    }
    // BN + residual + concat
    bn_stats<<<512, blk, 0, stream>>>(Y, a_g, a_be, b_g, b_be, ss);
    bn_apply<<<8192, blk, 0, stream>>>(Y, image, ss, out);
}